// Round 13
// baseline (1272.878 us; speedup 1.0000x reference)
//
#include <hip/hip_runtime.h>
#include <math.h>

// ---------------- Kernel A: reciprocal row norms ----------------
__global__ void rownorm_kernel(const float* __restrict__ x,
                               float* __restrict__ rnorm, int C) {
    int row = blockIdx.x;
    const float4* xr = (const float4*)(x + (size_t)row * C);
    int n4 = C >> 2;
    float s = 0.f;
    for (int c = threadIdx.x; c < n4; c += blockDim.x) {
        float4 v = xr[c];
        s += v.x * v.x + v.y * v.y + v.z * v.z + v.w * v.w;
    }
    for (int off = 32; off > 0; off >>= 1) s += __shfl_down(s, off, 64);
    __shared__ float red[4];
    int lane = threadIdx.x & 63, wid = threadIdx.x >> 6;
    if (lane == 0) red[wid] = s;
    __syncthreads();
    if (threadIdx.x == 0) {
        float t = red[0] + red[1] + red[2] + red[3];
        float n = fmaxf(sqrtf(t), 1e-6f);
        rnorm[row] = 1.0f / n;
    }
}

// ---------------- Kernel B: cosine = 1 - xn @ xn^T (fp32 vector GEMM) ------
// Symmetric output: only upper-triangle blocks compute; off-diag blocks
// write tile AND transpose (bitwise identical: same K summation order).
// Simple load->barrier->compute loop: at 4 resident blocks/CU the implicit
// TLP already hides global latency (R12's reg-staged dbuf REGRESSED -72us
// via VGPR pressure -> keep this form).
#define BM 128
#define BN 128
#define BK 32

__global__ __launch_bounds__(256) void cosine_gemm(
        const float* __restrict__ x, const float* __restrict__ rnorm,
        float* __restrict__ cosine, int L, int C) {
    if (blockIdx.x < blockIdx.y) return;  // lower triangle: skip
    __shared__ float As[BK][BM + 4];
    __shared__ float Bs[BK][BN + 4];
    const int tid = threadIdx.x;
    const int i0 = blockIdx.y * BM;
    const int j0 = blockIdx.x * BN;
    const int tr = (tid >> 4) << 3;
    const int tc = (tid & 15) << 3;
    const int lr = tid >> 3;
    const int lc = (tid & 7) << 2;
    float acc[8][8] = {};

    for (int k0 = 0; k0 < C; k0 += BK) {
#pragma unroll
        for (int q = 0; q < 4; ++q) {
            int r = lr + q * 32;
            float ra = rnorm[i0 + r];
            float4 va = *(const float4*)(x + (size_t)(i0 + r) * C + k0 + lc);
            As[lc + 0][r] = va.x * ra;
            As[lc + 1][r] = va.y * ra;
            As[lc + 2][r] = va.z * ra;
            As[lc + 3][r] = va.w * ra;
            float rb = rnorm[j0 + r];
            float4 vb = *(const float4*)(x + (size_t)(j0 + r) * C + k0 + lc);
            Bs[lc + 0][r] = vb.x * rb;
            Bs[lc + 1][r] = vb.y * rb;
            Bs[lc + 2][r] = vb.z * rb;
            Bs[lc + 3][r] = vb.w * rb;
        }
        __syncthreads();
#pragma unroll
        for (int kk = 0; kk < BK; ++kk) {
            float a[8], b[8];
#pragma unroll
            for (int m = 0; m < 8; ++m) a[m] = As[kk][tr + m];
#pragma unroll
            for (int n = 0; n < 8; ++n) b[n] = Bs[kk][tc + n];
#pragma unroll
            for (int m = 0; m < 8; ++m)
#pragma unroll
                for (int n = 0; n < 8; ++n)
                    acc[m][n] = fmaf(a[m], b[n], acc[m][n]);
        }
        __syncthreads();
    }
#pragma unroll
    for (int m = 0; m < 8; ++m) {
        float* crow = cosine + (size_t)(i0 + tr + m) * L + j0 + tc;
        float4 o0 = {1.f - acc[m][0], 1.f - acc[m][1], 1.f - acc[m][2], 1.f - acc[m][3]};
        float4 o1 = {1.f - acc[m][4], 1.f - acc[m][5], 1.f - acc[m][6], 1.f - acc[m][7]};
        ((float4*)crow)[0] = o0;
        ((float4*)crow)[1] = o1;
    }
    if (i0 != j0) {
#pragma unroll
        for (int n = 0; n < 8; ++n) {
            float* trow = cosine + (size_t)(j0 + tc + n) * L + i0 + tr;
            float4 t0 = {1.f - acc[0][n], 1.f - acc[1][n], 1.f - acc[2][n], 1.f - acc[3][n]};
            float4 t1 = {1.f - acc[4][n], 1.f - acc[5][n], 1.f - acc[6][n], 1.f - acc[7][n]};
            ((float4*)trow)[0] = t0;
            ((float4*)trow)[1] = t1;
        }
    }
}

// ---------------- Kernel C: second-smallest per row ----------------
__global__ void twosmallest_kernel(const float* __restrict__ cosine,
                                   float* __restrict__ min2, int L) {
    int row = blockIdx.x;
    const float4* r4 = (const float4*)(cosine + (size_t)row * L);
    float4 v0 = r4[threadIdx.x];
    float4 v1 = r4[threadIdx.x + 256];
    float4 v2 = r4[threadIdx.x + 512];
    float4 v3 = r4[threadIdx.x + 768];

#define PAIR_INIT(M1, M2, V)                                   \
    float M1 = fminf(V.x, V.y), M2 = fmaxf(V.x, V.y);          \
    { float _n1 = fminf(M1, V.z); M2 = fminf(M2, fmaxf(M1, V.z)); M1 = _n1; \
      _n1 = fminf(M1, V.w); M2 = fminf(M2, fmaxf(M1, V.w)); M1 = _n1; }
    PAIR_INIT(a1, a2, v0)
    PAIR_INIT(b1, b2, v1)
    PAIR_INIT(c1, c2, v2)
    PAIR_INIT(d1, d2, v3)
#undef PAIR_INIT
    float m1 = fminf(a1, b1), m2 = fminf(fmaxf(a1, b1), fminf(a2, b2));
    float n1 = fminf(c1, d1), n2 = fminf(fmaxf(c1, d1), fminf(c2, d2));
    float m1r = fminf(m1, n1), m2r = fminf(fmaxf(m1, n1), fminf(m2, n2));

    for (int off = 32; off > 0; off >>= 1) {
        float om1 = __shfl_down(m1r, off, 64);
        float om2 = __shfl_down(m2r, off, 64);
        float nm1 = fminf(m1r, om1);
        float nm2 = fminf(fmaxf(m1r, om1), fminf(m2r, om2));
        m1r = nm1; m2r = nm2;
    }
    __shared__ float s1[4], s2[4];
    int lane = threadIdx.x & 63, wid = threadIdx.x >> 6;
    if (lane == 0) { s1[wid] = m1r; s2[wid] = m2r; }
    __syncthreads();
    if (threadIdx.x == 0) {
        float x1 = s1[0], x2 = s2[0];
        for (int w = 1; w < 4; ++w) {
            float y1 = s1[w], y2 = s2[w];
            float z2 = fminf(fmaxf(x1, y1), fminf(x2, y2));
            x1 = fminf(x1, y1);
            x2 = z2;
        }
        min2[row] = x2;
    }
}

// ---------------- Kernel D: persistent greedy k-center ----------------
// R10 structure + 2nd-runner-up L2-warm touch (PF, double-buffered,
// consumed 2 steps later so its vmcnt wait never covers younger spec
// loads). Single runner-up register speculation; spec loads issued AFTER
// the hit/miss join (sched_barrier fenced). Barrier = lgkmcnt(0)+s_barrier.
#define FOR16(X) X(0) X(1) X(2) X(3) X(4) X(5) X(6) X(7) \
                 X(8) X(9) X(10) X(11) X(12) X(13) X(14) X(15)

#define ARGMAX16(BV, BJ)                                                      \
  do {                                                                        \
    float _t0,_t1,_t2,_t3,_t4,_t5,_t6,_t7;                                    \
    int _u0,_u1,_u2,_u3,_u4,_u5,_u6,_u7;                                      \
    bool _g;                                                                  \
    _g = sc1  > sc0;  _t0 = _g ? sc1  : sc0;  _u0 = _g ? base+1  : base+0;    \
    _g = sc3  > sc2;  _t1 = _g ? sc3  : sc2;  _u1 = _g ? base+3  : base+2;    \
    _g = sc5  > sc4;  _t2 = _g ? sc5  : sc4;  _u2 = _g ? base+5  : base+4;    \
    _g = sc7  > sc6;  _t3 = _g ? sc7  : sc6;  _u3 = _g ? base+7  : base+6;    \
    _g = sc9  > sc8;  _t4 = _g ? sc9  : sc8;  _u4 = _g ? base+9  : base+8;    \
    _g = sc11 > sc10; _t5 = _g ? sc11 : sc10; _u5 = _g ? base+11 : base+10;   \
    _g = sc13 > sc12; _t6 = _g ? sc13 : sc12; _u6 = _g ? base+13 : base+12;   \
    _g = sc15 > sc14; _t7 = _g ? sc15 : sc14; _u7 = _g ? base+15 : base+14;   \
    _g = _t1 > _t0; _t0 = _g ? _t1 : _t0; _u0 = _g ? _u1 : _u0;               \
    _g = _t3 > _t2; _t2 = _g ? _t3 : _t2; _u2 = _g ? _u3 : _u2;               \
    _g = _t5 > _t4; _t4 = _g ? _t5 : _t4; _u4 = _g ? _u5 : _u4;               \
    _g = _t7 > _t6; _t6 = _g ? _t7 : _t6; _u6 = _g ? _u7 : _u6;               \
    _g = _t2 > _t0; _t0 = _g ? _t2 : _t0; _u0 = _g ? _u2 : _u0;               \
    _g = _t6 > _t4; _t4 = _g ? _t6 : _t4; _u4 = _g ? _u6 : _u4;               \
    _g = _t4 > _t0; BV = _g ? _t4 : _t0; BJ = _g ? _u4 : _u0;                 \
  } while (0)

#define DPP_FMAX(V, CTRL)                                                     \
  do {                                                                        \
    int _b = __builtin_amdgcn_update_dpp(                                     \
        __float_as_int(V), __float_as_int(V), (CTRL), 0xf, 0xf, false);       \
    (V) = fmaxf((V), __int_as_float(_b));                                     \
  } while (0)

// barrier that does NOT drain vmcnt (spec/touch loads stay in flight)
#define BAR_NOVM()                                                \
  do {                                                            \
    asm volatile("s_waitcnt lgkmcnt(0)" ::: "memory");            \
    __builtin_amdgcn_s_barrier();                                 \
    asm volatile("" ::: "memory");                                \
  } while (0)

static __device__ __forceinline__ void wave_argmax(float bv, int bj,
                                                   float& wv, int& wj) {
    float v = bv;
    DPP_FMAX(v, 0x111);  // row_shr:1
    DPP_FMAX(v, 0x112);  // row_shr:2
    DPP_FMAX(v, 0x114);  // row_shr:4
    DPP_FMAX(v, 0x118);  // row_shr:8
    DPP_FMAX(v, 0x142);  // row_bcast:15
    DPP_FMAX(v, 0x143);  // row_bcast:31 -> lane63 = wave max
    float wmax = __int_as_float(
        __builtin_amdgcn_readlane(__float_as_int(v), 63));
    unsigned long long m = __ballot(bv == wmax);
    int lowlane = __ffsll((unsigned long long)m) - 1;
    wj = __builtin_amdgcn_readlane(bj, lowlane);
    wv = wmax;
}

// One greedy step. PIN*: spec regs filled last step (valid if winner==PREDIN).
// POUT*: spec regs this step fills. PF: 2nd-runner-up touch reg, consumed
// 2 steps later (top of next same-parity step; older than all in-flight).
#define GSTEP(PIN0,PIN1,PIN2,PIN3, PREDIN, POUT0,POUT1,POUT2,POUT3, PREDOUT, PF) \
  {                                                                           \
    dummy += PF; /* consume 2-step-old touch: fully shadowed, old vmcnt */    \
    float wv_; int wj_;                                                       \
    wave_argmax(bv, bj, wv_, wj_);                                            \
    if (lane == 0) { sv[p][wid] = wv_; si[p][wid] = wj_; }                    \
    BAR_NOVM();                                                               \
    float4 cv4 = *(const float4*)&sv[p][0];                                   \
    int4 ci4 = *(const int4*)&si[p][0];                                       \
    p ^= 1;                                                                   \
    float cwv = cv4.x; int wi_ = ci4.x; int wsl = 0;                          \
    if (cv4.y > cwv) { cwv = cv4.y; wi_ = ci4.y; wsl = 1; }                   \
    if (cv4.z > cwv) { cwv = cv4.z; wi_ = ci4.z; wsl = 2; }                   \
    if (cv4.w > cwv) { cwv = cv4.w; wi_ = ci4.w; wsl = 3; }                   \
    int wiu = __builtin_amdgcn_readfirstlane(wi_);                            \
    float e0 = (wsl == 0) ? -INFINITY : cv4.x;                                \
    float e1 = (wsl == 1) ? -INFINITY : cv4.y;                                \
    float e2 = (wsl == 2) ? -INFINITY : cv4.z;                                \
    float e3 = (wsl == 3) ? -INFINITY : cv4.w;                                \
    float rv = e0; int ri_ = ci4.x; int rsl = 0;                              \
    if (e1 > rv) { rv = e1; ri_ = ci4.y; rsl = 1; }                           \
    if (e2 > rv) { rv = e2; ri_ = ci4.z; rsl = 2; }                           \
    if (e3 > rv) { rv = e3; ri_ = ci4.w; rsl = 3; }                           \
    int riu = __builtin_amdgcn_readfirstlane(ri_);                            \
    float f0 = (rsl == 0) ? -INFINITY : e0;                                   \
    float f1 = (rsl == 1) ? -INFINITY : e1;                                   \
    float f2 = (rsl == 2) ? -INFINITY : e2;                                   \
    float f3 = (rsl == 3) ? -INFINITY : e3;                                   \
    float rv2 = f0; int ri2_ = ci4.x;                                         \
    if (f1 > rv2) { rv2 = f1; ri2_ = ci4.y; }                                 \
    if (f2 > rv2) { rv2 = f2; ri2_ = ci4.z; }                                 \
    if (f3 > rv2) { rv2 = f3; ri2_ = ci4.w; }                                 \
    int ri2u = __builtin_amdgcn_readfirstlane(ri2_);                          \
    /* winner data: spec hit (uniform branch; in-branch waitcnt covers */     \
    /* only last-step loads) or fallback load (L2-warm if touched) */         \
    float4 q0, q1, q2, q3;                                                    \
    if (wiu == PREDIN) {                                                      \
        q0 = PIN0; q1 = PIN1; q2 = PIN2; q3 = PIN3;                           \
    } else {                                                                  \
        const float4* rp_ = (const float4*)(cosine + (size_t)wiu * L) + (tid<<2); \
        q0 = rp_[0]; q1 = rp_[1]; q2 = rp_[2]; q3 = rp_[3];                   \
    }                                                                         \
    __builtin_amdgcn_sched_barrier(0);                                        \
    /* next-step spec + 2nd-runner-up touch AFTER the join (fenced) */        \
    const float4* sp_ = (const float4*)(cosine + (size_t)riu * L) + (tid<<2); \
    POUT0 = sp_[0]; POUT1 = sp_[1]; POUT2 = sp_[2]; POUT3 = sp_[3];           \
    PREDOUT = riu;                                                            \
    PF = *(cosine + (size_t)ri2u * L + (tid << 4));                           \
    __builtin_amdgcn_sched_barrier(0);                                        \
    int sl = ((wiu >> 4) == tid) ? (wiu & 15) : -1;                           \
    sc0  = (sl == 0)  ? -INFINITY : fminf(sc0, q0.x);                         \
    sc1  = (sl == 1)  ? -INFINITY : fminf(sc1, q0.y);                         \
    sc2  = (sl == 2)  ? -INFINITY : fminf(sc2, q0.z);                         \
    sc3  = (sl == 3)  ? -INFINITY : fminf(sc3, q0.w);                         \
    sc4  = (sl == 4)  ? -INFINITY : fminf(sc4, q1.x);                         \
    sc5  = (sl == 5)  ? -INFINITY : fminf(sc5, q1.y);                         \
    sc6  = (sl == 6)  ? -INFINITY : fminf(sc6, q1.z);                         \
    sc7  = (sl == 7)  ? -INFINITY : fminf(sc7, q1.w);                         \
    sc8  = (sl == 8)  ? -INFINITY : fminf(sc8, q2.x);                         \
    sc9  = (sl == 9)  ? -INFINITY : fminf(sc9, q2.y);                         \
    sc10 = (sl == 10) ? -INFINITY : fminf(sc10, q2.z);                        \
    sc11 = (sl == 11) ? -INFINITY : fminf(sc11, q2.w);                        \
    sc12 = (sl == 12) ? -INFINITY : fminf(sc12, q3.x);                        \
    sc13 = (sl == 13) ? -INFINITY : fminf(sc13, q3.y);                        \
    sc14 = (sl == 14) ? -INFINITY : fminf(sc14, q3.z);                        \
    sc15 = (sl == 15) ? -INFINITY : fminf(sc15, q3.w);                        \
    ARGMAX16(bv, bj);                                                         \
  }

__global__ __launch_bounds__(256) void greedy_kernel(
        const float* __restrict__ cosine, const float* __restrict__ min2,
        float* __restrict__ sel_out, int L, int k) {
    const int tid = threadIdx.x;
    const int lane = tid & 63, wid = tid >> 6;
    __shared__ __align__(16) float sv[2][4];
    __shared__ __align__(16) int si[2][4];
    __shared__ int wsum[4];
    const int base = tid << 4;

#define DECL_SC(i) float sc##i;
    FOR16(DECL_SC)

    float bv; int bj;

    // ---- first = argmax(min2) ----
    {
        const float4* m4 = (const float4*)min2 + (tid << 2);
        float4 q0 = m4[0], q1 = m4[1], q2 = m4[2], q3 = m4[3];
        sc0 = q0.x;  sc1 = q0.y;  sc2 = q0.z;  sc3 = q0.w;
        sc4 = q1.x;  sc5 = q1.y;  sc6 = q1.z;  sc7 = q1.w;
        sc8 = q2.x;  sc9 = q2.y;  sc10 = q2.z; sc11 = q2.w;
        sc12 = q3.x; sc13 = q3.y; sc14 = q3.z; sc15 = q3.w;
    }
    ARGMAX16(bv, bj);
    {
        float wv; int wj;
        wave_argmax(bv, bj, wv, wj);
        if (lane == 0) { sv[0][wid] = wv; si[0][wid] = wj; }
    }
    __syncthreads();
    int first;
    {
        float4 cv4 = *(const float4*)&sv[0][0];
        int4 ci4 = *(const int4*)&si[0][0];
        float wv = cv4.x; int wi = ci4.x;
        if (cv4.y > wv) { wv = cv4.y; wi = ci4.y; }
        if (cv4.z > wv) { wv = cv4.z; wi = ci4.z; }
        if (cv4.w > wv) { wv = cv4.w; wi = ci4.w; }
        first = __builtin_amdgcn_readfirstlane(wi);
    }
    {
        const float4* rp = (const float4*)(cosine + (size_t)first * L) + (tid << 2);
        float4 q0 = rp[0], q1 = rp[1], q2 = rp[2], q3 = rp[3];
        int sl = ((first >> 4) == tid) ? (first & 15) : -1;
        sc0  = (sl == 0)  ? -INFINITY : q0.x;
        sc1  = (sl == 1)  ? -INFINITY : q0.y;
        sc2  = (sl == 2)  ? -INFINITY : q0.z;
        sc3  = (sl == 3)  ? -INFINITY : q0.w;
        sc4  = (sl == 4)  ? -INFINITY : q1.x;
        sc5  = (sl == 5)  ? -INFINITY : q1.y;
        sc6  = (sl == 6)  ? -INFINITY : q1.z;
        sc7  = (sl == 7)  ? -INFINITY : q1.w;
        sc8  = (sl == 8)  ? -INFINITY : q2.x;
        sc9  = (sl == 9)  ? -INFINITY : q2.y;
        sc10 = (sl == 10) ? -INFINITY : q2.z;
        sc11 = (sl == 11) ? -INFINITY : q2.w;
        sc12 = (sl == 12) ? -INFINITY : q3.x;
        sc13 = (sl == 13) ? -INFINITY : q3.y;
        sc14 = (sl == 14) ? -INFINITY : q3.z;
        sc15 = (sl == 15) ? -INFINITY : q3.w;
    }
    ARGMAX16(bv, bj);

    // ---- k-1 greedy steps: 2x unrolled, alternating spec + touch sets ----
    int p = 1;
    float dummy = 0.f, pfA = 0.f, pfB = 0.f;
    int predA = -1, predB = -1;
    float4 a0 = {0,0,0,0}, a1 = {0,0,0,0}, a2 = {0,0,0,0}, a3 = {0,0,0,0};
    float4 b0 = {0,0,0,0}, b1 = {0,0,0,0}, b2 = {0,0,0,0}, b3 = {0,0,0,0};
    int it = 0;
    for (; it + 1 < k - 1; it += 2) {
        GSTEP(a0,a1,a2,a3, predA, b0,b1,b2,b3, predB, pfA)
        GSTEP(b0,b1,b2,b3, predB, a0,a1,a2,a3, predA, pfB)
    }
    if (it < k - 1) {
        GSTEP(a0,a1,a2,a3, predA, b0,b1,b2,b3, predB, pfA)
    }
    asm volatile("" :: "v"(b0.x), "v"(b1.x), "v"(b2.x), "v"(b3.x),
                       "v"(a0.x), "v"(a1.x), "v"(a2.x), "v"(a3.x),
                       "v"(dummy), "v"(pfA), "v"(pfB));

    // ---- compact selected (score == -inf) in ascending index order ----
    unsigned flags = 0; int cnt = 0;
#define FLAGBIT(i) if (sc##i == -INFINITY) { flags |= (1u << i); ++cnt; }
    FOR16(FLAGBIT)
    int incl = cnt;
#pragma unroll
    for (int off = 1; off < 64; off <<= 1) {
        int n = __shfl_up(incl, off, 64);
        if (lane >= off) incl += n;
    }
    if (lane == 63) wsum[wid] = incl;
    __syncthreads();
    int off0 = 0;
#pragma unroll
    for (int w = 0; w < 4; ++w)
        if (w < wid) off0 += wsum[w];
    int pos = off0 + incl - cnt;
#pragma unroll
    for (int j = 0; j < 16; ++j)
        if ((flags >> j) & 1) sel_out[pos++] = (float)(base + j);
}

// ---------------- launch ----------------
extern "C" void kernel_launch(void* const* d_in, const int* in_sizes, int n_in,
                              void* d_out, int out_size, void* d_ws, size_t ws_size,
                              hipStream_t stream) {
    const float* x = (const float*)d_in[0];

    long long L = (long long)floor(sqrt((double)out_size));
    while (L * L > (long long)out_size) --L;
    while ((L + 1) * (L + 1) <= (long long)out_size) ++L;
    long long k = (long long)out_size - L * L;
    long long C = (long long)in_sizes[0] / L;

    float* sel = (float*)d_out;
    float* cosine = (float*)d_out + k;
    float* rnorm = (float*)d_ws;
    float* min2 = rnorm + L;

    rownorm_kernel<<<(int)L, 256, 0, stream>>>(x, rnorm, (int)C);
    dim3 g2((int)(L / BN), (int)(L / BM));
    cosine_gemm<<<g2, 256, 0, stream>>>(x, rnorm, cosine, (int)L, (int)C);
    twosmallest_kernel<<<(int)L, 256, 0, stream>>>(cosine, min2, (int)L);
    greedy_kernel<<<1, 256, 0, stream>>>(cosine, min2, sel, (int)L, (int)k);
}

// Round 14
// 1175.683 us; speedup vs baseline: 1.0827x; 1.0827x over previous
//
#include <hip/hip_runtime.h>
#include <math.h>

// ---------------- Kernel A: reciprocal row norms ----------------
__global__ void rownorm_kernel(const float* __restrict__ x,
                               float* __restrict__ rnorm, int C) {
    int row = blockIdx.x;
    const float4* xr = (const float4*)(x + (size_t)row * C);
    int n4 = C >> 2;
    float s = 0.f;
    for (int c = threadIdx.x; c < n4; c += blockDim.x) {
        float4 v = xr[c];
        s += v.x * v.x + v.y * v.y + v.z * v.z + v.w * v.w;
    }
    for (int off = 32; off > 0; off >>= 1) s += __shfl_down(s, off, 64);
    __shared__ float red[4];
    int lane = threadIdx.x & 63, wid = threadIdx.x >> 6;
    if (lane == 0) red[wid] = s;
    __syncthreads();
    if (threadIdx.x == 0) {
        float t = red[0] + red[1] + red[2] + red[3];
        float n = fmaxf(sqrtf(t), 1e-6f);
        rnorm[row] = 1.0f / n;
    }
}

// ---------------- Kernel B: cosine = 1 - xn @ xn^T (fp32 vector GEMM) ------
// Symmetric output: only upper-triangle blocks compute; off-diag blocks
// write tile AND transpose (bitwise identical: same K summation order).
// Simple load->barrier->compute loop: at 4 resident blocks/CU the implicit
// TLP already hides global latency (reg-staged dbuf REGRESSED via VGPR
// pressure -> keep this form).
#define BM 128
#define BN 128
#define BK 32

__global__ __launch_bounds__(256) void cosine_gemm(
        const float* __restrict__ x, const float* __restrict__ rnorm,
        float* __restrict__ cosine, int L, int C) {
    if (blockIdx.x < blockIdx.y) return;  // lower triangle: skip
    __shared__ float As[BK][BM + 4];
    __shared__ float Bs[BK][BN + 4];
    const int tid = threadIdx.x;
    const int i0 = blockIdx.y * BM;
    const int j0 = blockIdx.x * BN;
    const int tr = (tid >> 4) << 3;
    const int tc = (tid & 15) << 3;
    const int lr = tid >> 3;
    const int lc = (tid & 7) << 2;
    float acc[8][8] = {};

    for (int k0 = 0; k0 < C; k0 += BK) {
#pragma unroll
        for (int q = 0; q < 4; ++q) {
            int r = lr + q * 32;
            float ra = rnorm[i0 + r];
            float4 va = *(const float4*)(x + (size_t)(i0 + r) * C + k0 + lc);
            As[lc + 0][r] = va.x * ra;
            As[lc + 1][r] = va.y * ra;
            As[lc + 2][r] = va.z * ra;
            As[lc + 3][r] = va.w * ra;
            float rb = rnorm[j0 + r];
            float4 vb = *(const float4*)(x + (size_t)(j0 + r) * C + k0 + lc);
            Bs[lc + 0][r] = vb.x * rb;
            Bs[lc + 1][r] = vb.y * rb;
            Bs[lc + 2][r] = vb.z * rb;
            Bs[lc + 3][r] = vb.w * rb;
        }
        __syncthreads();
#pragma unroll
        for (int kk = 0; kk < BK; ++kk) {
            float a[8], b[8];
#pragma unroll
            for (int m = 0; m < 8; ++m) a[m] = As[kk][tr + m];
#pragma unroll
            for (int n = 0; n < 8; ++n) b[n] = Bs[kk][tc + n];
#pragma unroll
            for (int m = 0; m < 8; ++m)
#pragma unroll
                for (int n = 0; n < 8; ++n)
                    acc[m][n] = fmaf(a[m], b[n], acc[m][n]);
        }
        __syncthreads();
    }
#pragma unroll
    for (int m = 0; m < 8; ++m) {
        float* crow = cosine + (size_t)(i0 + tr + m) * L + j0 + tc;
        float4 o0 = {1.f - acc[m][0], 1.f - acc[m][1], 1.f - acc[m][2], 1.f - acc[m][3]};
        float4 o1 = {1.f - acc[m][4], 1.f - acc[m][5], 1.f - acc[m][6], 1.f - acc[m][7]};
        ((float4*)crow)[0] = o0;
        ((float4*)crow)[1] = o1;
    }
    if (i0 != j0) {
#pragma unroll
        for (int n = 0; n < 8; ++n) {
            float* trow = cosine + (size_t)(j0 + tc + n) * L + i0 + tr;
            float4 t0 = {1.f - acc[0][n], 1.f - acc[1][n], 1.f - acc[2][n], 1.f - acc[3][n]};
            float4 t1 = {1.f - acc[4][n], 1.f - acc[5][n], 1.f - acc[6][n], 1.f - acc[7][n]};
            ((float4*)trow)[0] = t0;
            ((float4*)trow)[1] = t1;
        }
    }
}

// ---------------- Kernel C: second-smallest per row ----------------
__global__ void twosmallest_kernel(const float* __restrict__ cosine,
                                   float* __restrict__ min2, int L) {
    int row = blockIdx.x;
    const float4* r4 = (const float4*)(cosine + (size_t)row * L);
    float4 v0 = r4[threadIdx.x];
    float4 v1 = r4[threadIdx.x + 256];
    float4 v2 = r4[threadIdx.x + 512];
    float4 v3 = r4[threadIdx.x + 768];

#define PAIR_INIT(M1, M2, V)                                   \
    float M1 = fminf(V.x, V.y), M2 = fmaxf(V.x, V.y);          \
    { float _n1 = fminf(M1, V.z); M2 = fminf(M2, fmaxf(M1, V.z)); M1 = _n1; \
      _n1 = fminf(M1, V.w); M2 = fminf(M2, fmaxf(M1, V.w)); M1 = _n1; }
    PAIR_INIT(a1, a2, v0)
    PAIR_INIT(b1, b2, v1)
    PAIR_INIT(c1, c2, v2)
    PAIR_INIT(d1, d2, v3)
#undef PAIR_INIT
    float m1 = fminf(a1, b1), m2 = fminf(fmaxf(a1, b1), fminf(a2, b2));
    float n1 = fminf(c1, d1), n2 = fminf(fmaxf(c1, d1), fminf(c2, d2));
    float m1r = fminf(m1, n1), m2r = fminf(fmaxf(m1, n1), fminf(m2, n2));

    for (int off = 32; off > 0; off >>= 1) {
        float om1 = __shfl_down(m1r, off, 64);
        float om2 = __shfl_down(m2r, off, 64);
        float nm1 = fminf(m1r, om1);
        float nm2 = fminf(fmaxf(m1r, om1), fminf(m2r, om2));
        m1r = nm1; m2r = nm2;
    }
    __shared__ float s1[4], s2[4];
    int lane = threadIdx.x & 63, wid = threadIdx.x >> 6;
    if (lane == 0) { s1[wid] = m1r; s2[wid] = m2r; }
    __syncthreads();
    if (threadIdx.x == 0) {
        float x1 = s1[0], x2 = s2[0];
        for (int w = 1; w < 4; ++w) {
            float y1 = s1[w], y2 = s2[w];
            float z2 = fminf(fmaxf(x1, y1), fminf(x2, y2));
            x1 = fminf(x1, y1);
            x2 = z2;
        }
        min2[row] = x2;
    }
}

// ---------------- Kernel D: persistent greedy k-center (R10-exact) --------
// 1 block x 256 threads (4 waves). Thread t owns scores [16t,16t+16) in 16
// named scalars. Single runner-up speculation; spec loads issued AFTER the
// hit/miss join (sched_barrier fenced) so hit-path waits cover only
// last-step loads. Barrier = lgkmcnt(0)+s_barrier (no vmcnt drain).
#define FOR16(X) X(0) X(1) X(2) X(3) X(4) X(5) X(6) X(7) \
                 X(8) X(9) X(10) X(11) X(12) X(13) X(14) X(15)

#define ARGMAX16(BV, BJ)                                                      \
  do {                                                                        \
    float _t0,_t1,_t2,_t3,_t4,_t5,_t6,_t7;                                    \
    int _u0,_u1,_u2,_u3,_u4,_u5,_u6,_u7;                                      \
    bool _g;                                                                  \
    _g = sc1  > sc0;  _t0 = _g ? sc1  : sc0;  _u0 = _g ? base+1  : base+0;    \
    _g = sc3  > sc2;  _t1 = _g ? sc3  : sc2;  _u1 = _g ? base+3  : base+2;    \
    _g = sc5  > sc4;  _t2 = _g ? sc5  : sc4;  _u2 = _g ? base+5  : base+4;    \
    _g = sc7  > sc6;  _t3 = _g ? sc7  : sc6;  _u3 = _g ? base+7  : base+6;    \
    _g = sc9  > sc8;  _t4 = _g ? sc9  : sc8;  _u4 = _g ? base+9  : base+8;    \
    _g = sc11 > sc10; _t5 = _g ? sc11 : sc10; _u5 = _g ? base+11 : base+10;   \
    _g = sc13 > sc12; _t6 = _g ? sc13 : sc12; _u6 = _g ? base+13 : base+12;   \
    _g = sc15 > sc14; _t7 = _g ? sc15 : sc14; _u7 = _g ? base+15 : base+14;   \
    _g = _t1 > _t0; _t0 = _g ? _t1 : _t0; _u0 = _g ? _u1 : _u0;               \
    _g = _t3 > _t2; _t2 = _g ? _t3 : _t2; _u2 = _g ? _u3 : _u2;               \
    _g = _t5 > _t4; _t4 = _g ? _t5 : _t4; _u4 = _g ? _u5 : _u4;               \
    _g = _t7 > _t6; _t6 = _g ? _t7 : _t6; _u6 = _g ? _u7 : _u6;               \
    _g = _t2 > _t0; _t0 = _g ? _t2 : _t0; _u0 = _g ? _u2 : _u0;               \
    _g = _t6 > _t4; _t4 = _g ? _t6 : _t4; _u4 = _g ? _u6 : _u4;               \
    _g = _t4 > _t0; BV = _g ? _t4 : _t0; BJ = _g ? _u4 : _u0;                 \
  } while (0)

#define DPP_FMAX(V, CTRL)                                                     \
  do {                                                                        \
    int _b = __builtin_amdgcn_update_dpp(                                     \
        __float_as_int(V), __float_as_int(V), (CTRL), 0xf, 0xf, false);       \
    (V) = fmaxf((V), __int_as_float(_b));                                     \
  } while (0)

// barrier that does NOT drain vmcnt (spec loads stay in flight)
#define BAR_NOVM()                                                \
  do {                                                            \
    asm volatile("s_waitcnt lgkmcnt(0)" ::: "memory");            \
    __builtin_amdgcn_s_barrier();                                 \
    asm volatile("" ::: "memory");                                \
  } while (0)

static __device__ __forceinline__ void wave_argmax(float bv, int bj,
                                                   float& wv, int& wj) {
    float v = bv;
    DPP_FMAX(v, 0x111);  // row_shr:1
    DPP_FMAX(v, 0x112);  // row_shr:2
    DPP_FMAX(v, 0x114);  // row_shr:4
    DPP_FMAX(v, 0x118);  // row_shr:8
    DPP_FMAX(v, 0x142);  // row_bcast:15
    DPP_FMAX(v, 0x143);  // row_bcast:31 -> lane63 = wave max
    float wmax = __int_as_float(
        __builtin_amdgcn_readlane(__float_as_int(v), 63));
    unsigned long long m = __ballot(bv == wmax);
    int lowlane = __ffsll((unsigned long long)m) - 1;
    wj = __builtin_amdgcn_readlane(bj, lowlane);
    wv = wmax;
}

// One greedy step. PIN*: spec regs filled last step (valid if winner==PREDIN).
// POUT*: spec regs this step fills for next step (issued AFTER the q join).
#define GSTEP(PIN0,PIN1,PIN2,PIN3, PREDIN, POUT0,POUT1,POUT2,POUT3, PREDOUT)  \
  {                                                                           \
    float wv_; int wj_;                                                       \
    wave_argmax(bv, bj, wv_, wj_);                                            \
    if (lane == 0) { sv[p][wid] = wv_; si[p][wid] = wj_; }                    \
    BAR_NOVM();                                                               \
    float4 cv4 = *(const float4*)&sv[p][0];                                   \
    int4 ci4 = *(const int4*)&si[p][0];                                       \
    p ^= 1;                                                                   \
    float cwv = cv4.x; int wi_ = ci4.x; int wsl = 0;                          \
    if (cv4.y > cwv) { cwv = cv4.y; wi_ = ci4.y; wsl = 1; }                   \
    if (cv4.z > cwv) { cwv = cv4.z; wi_ = ci4.z; wsl = 2; }                   \
    if (cv4.w > cwv) { cwv = cv4.w; wi_ = ci4.w; wsl = 3; }                   \
    int wiu = __builtin_amdgcn_readfirstlane(wi_);                            \
    float e0 = (wsl == 0) ? -INFINITY : cv4.x;                                \
    float e1 = (wsl == 1) ? -INFINITY : cv4.y;                                \
    float e2 = (wsl == 2) ? -INFINITY : cv4.z;                                \
    float e3 = (wsl == 3) ? -INFINITY : cv4.w;                                \
    float rv = e0; int ri_ = ci4.x;                                           \
    if (e1 > rv) { rv = e1; ri_ = ci4.y; }                                    \
    if (e2 > rv) { rv = e2; ri_ = ci4.z; }                                    \
    if (e3 > rv) { rv = e3; ri_ = ci4.w; }                                    \
    int riu = __builtin_amdgcn_readfirstlane(ri_);                            \
    /* winner data: spec hit (uniform branch; waitcnt lands IN-branch and */  \
    /* covers only last-step loads) or fallback load */                       \
    float4 q0, q1, q2, q3;                                                    \
    if (wiu == PREDIN) {                                                      \
        q0 = PIN0; q1 = PIN1; q2 = PIN2; q3 = PIN3;                           \
    } else {                                                                  \
        const float4* rp_ = (const float4*)(cosine + (size_t)wiu * L) + (tid<<2); \
        q0 = rp_[0]; q1 = rp_[1]; q2 = rp_[2]; q3 = rp_[3];                   \
    }                                                                         \
    __builtin_amdgcn_sched_barrier(0);                                        \
    /* issue next-step spec AFTER the join: can't be hoisted above (fence) */ \
    const float4* sp_ = (const float4*)(cosine + (size_t)riu * L) + (tid<<2); \
    POUT0 = sp_[0]; POUT1 = sp_[1]; POUT2 = sp_[2]; POUT3 = sp_[3];           \
    PREDOUT = riu;                                                            \
    __builtin_amdgcn_sched_barrier(0);                                        \
    int sl = ((wiu >> 4) == tid) ? (wiu & 15) : -1;                           \
    sc0  = (sl == 0)  ? -INFINITY : fminf(sc0, q0.x);                         \
    sc1  = (sl == 1)  ? -INFINITY : fminf(sc1, q0.y);                         \
    sc2  = (sl == 2)  ? -INFINITY : fminf(sc2, q0.z);                         \
    sc3  = (sl == 3)  ? -INFINITY : fminf(sc3, q0.w);                         \
    sc4  = (sl == 4)  ? -INFINITY : fminf(sc4, q1.x);                         \
    sc5  = (sl == 5)  ? -INFINITY : fminf(sc5, q1.y);                         \
    sc6  = (sl == 6)  ? -INFINITY : fminf(sc6, q1.z);                         \
    sc7  = (sl == 7)  ? -INFINITY : fminf(sc7, q1.w);                         \
    sc8  = (sl == 8)  ? -INFINITY : fminf(sc8, q2.x);                         \
    sc9  = (sl == 9)  ? -INFINITY : fminf(sc9, q2.y);                         \
    sc10 = (sl == 10) ? -INFINITY : fminf(sc10, q2.z);                        \
    sc11 = (sl == 11) ? -INFINITY : fminf(sc11, q2.w);                        \
    sc12 = (sl == 12) ? -INFINITY : fminf(sc12, q3.x);                        \
    sc13 = (sl == 13) ? -INFINITY : fminf(sc13, q3.y);                        \
    sc14 = (sl == 14) ? -INFINITY : fminf(sc14, q3.z);                        \
    sc15 = (sl == 15) ? -INFINITY : fminf(sc15, q3.w);                        \
    ARGMAX16(bv, bj);                                                         \
  }

__global__ __launch_bounds__(256) void greedy_kernel(
        const float* __restrict__ cosine, const float* __restrict__ min2,
        float* __restrict__ sel_out, int L, int k) {
    const int tid = threadIdx.x;
    const int lane = tid & 63, wid = tid >> 6;
    __shared__ __align__(16) float sv[2][4];
    __shared__ __align__(16) int si[2][4];
    __shared__ int wsum[4];
    const int base = tid << 4;

#define DECL_SC(i) float sc##i;
    FOR16(DECL_SC)

    float bv; int bj;

    // ---- first = argmax(min2) ----
    {
        const float4* m4 = (const float4*)min2 + (tid << 2);
        float4 q0 = m4[0], q1 = m4[1], q2 = m4[2], q3 = m4[3];
        sc0 = q0.x;  sc1 = q0.y;  sc2 = q0.z;  sc3 = q0.w;
        sc4 = q1.x;  sc5 = q1.y;  sc6 = q1.z;  sc7 = q1.w;
        sc8 = q2.x;  sc9 = q2.y;  sc10 = q2.z; sc11 = q2.w;
        sc12 = q3.x; sc13 = q3.y; sc14 = q3.z; sc15 = q3.w;
    }
    ARGMAX16(bv, bj);
    {
        float wv; int wj;
        wave_argmax(bv, bj, wv, wj);
        if (lane == 0) { sv[0][wid] = wv; si[0][wid] = wj; }
    }
    __syncthreads();
    int first;
    {
        float4 cv4 = *(const float4*)&sv[0][0];
        int4 ci4 = *(const int4*)&si[0][0];
        float wv = cv4.x; int wi = ci4.x;
        if (cv4.y > wv) { wv = cv4.y; wi = ci4.y; }
        if (cv4.z > wv) { wv = cv4.z; wi = ci4.z; }
        if (cv4.w > wv) { wv = cv4.w; wi = ci4.w; }
        first = __builtin_amdgcn_readfirstlane(wi);
    }
    {
        const float4* rp = (const float4*)(cosine + (size_t)first * L) + (tid << 2);
        float4 q0 = rp[0], q1 = rp[1], q2 = rp[2], q3 = rp[3];
        int sl = ((first >> 4) == tid) ? (first & 15) : -1;
        sc0  = (sl == 0)  ? -INFINITY : q0.x;
        sc1  = (sl == 1)  ? -INFINITY : q0.y;
        sc2  = (sl == 2)  ? -INFINITY : q0.z;
        sc3  = (sl == 3)  ? -INFINITY : q0.w;
        sc4  = (sl == 4)  ? -INFINITY : q1.x;
        sc5  = (sl == 5)  ? -INFINITY : q1.y;
        sc6  = (sl == 6)  ? -INFINITY : q1.z;
        sc7  = (sl == 7)  ? -INFINITY : q1.w;
        sc8  = (sl == 8)  ? -INFINITY : q2.x;
        sc9  = (sl == 9)  ? -INFINITY : q2.y;
        sc10 = (sl == 10) ? -INFINITY : q2.z;
        sc11 = (sl == 11) ? -INFINITY : q2.w;
        sc12 = (sl == 12) ? -INFINITY : q3.x;
        sc13 = (sl == 13) ? -INFINITY : q3.y;
        sc14 = (sl == 14) ? -INFINITY : q3.z;
        sc15 = (sl == 15) ? -INFINITY : q3.w;
    }
    ARGMAX16(bv, bj);

    // ---- k-1 greedy steps: 2x unrolled, alternating spec sets ----
    int p = 1;
    int predA = -1, predB = -1;
    float4 a0 = {0,0,0,0}, a1 = {0,0,0,0}, a2 = {0,0,0,0}, a3 = {0,0,0,0};
    float4 b0 = {0,0,0,0}, b1 = {0,0,0,0}, b2 = {0,0,0,0}, b3 = {0,0,0,0};
    int it = 0;
    for (; it + 1 < k - 1; it += 2) {
        GSTEP(a0,a1,a2,a3, predA, b0,b1,b2,b3, predB)
        GSTEP(b0,b1,b2,b3, predB, a0,a1,a2,a3, predA)
    }
    if (it < k - 1) {
        GSTEP(a0,a1,a2,a3, predA, b0,b1,b2,b3, predB)
    }
    asm volatile("" :: "v"(b0.x), "v"(b1.x), "v"(b2.x), "v"(b3.x),
                       "v"(a0.x), "v"(a1.x), "v"(a2.x), "v"(a3.x));

    // ---- compact selected (score == -inf) in ascending index order ----
    unsigned flags = 0; int cnt = 0;
#define FLAGBIT(i) if (sc##i == -INFINITY) { flags |= (1u << i); ++cnt; }
    FOR16(FLAGBIT)
    int incl = cnt;
#pragma unroll
    for (int off = 1; off < 64; off <<= 1) {
        int n = __shfl_up(incl, off, 64);
        if (lane >= off) incl += n;
    }
    if (lane == 63) wsum[wid] = incl;
    __syncthreads();
    int off0 = 0;
#pragma unroll
    for (int w = 0; w < 4; ++w)
        if (w < wid) off0 += wsum[w];
    int pos = off0 + incl - cnt;
#pragma unroll
    for (int j = 0; j < 16; ++j)
        if ((flags >> j) & 1) sel_out[pos++] = (float)(base + j);
}

// ---------------- launch ----------------
extern "C" void kernel_launch(void* const* d_in, const int* in_sizes, int n_in,
                              void* d_out, int out_size, void* d_ws, size_t ws_size,
                              hipStream_t stream) {
    const float* x = (const float*)d_in[0];

    long long L = (long long)floor(sqrt((double)out_size));
    while (L * L > (long long)out_size) --L;
    while ((L + 1) * (L + 1) <= (long long)out_size) ++L;
    long long k = (long long)out_size - L * L;
    long long C = (long long)in_sizes[0] / L;

    float* sel = (float*)d_out;
    float* cosine = (float*)d_out + k;
    float* rnorm = (float*)d_ws;
    float* min2 = rnorm + L;

    rownorm_kernel<<<(int)L, 256, 0, stream>>>(x, rnorm, (int)C);
    dim3 g2((int)(L / BN), (int)(L / BM));
    cosine_gemm<<<g2, 256, 0, stream>>>(x, rnorm, cosine, (int)L, (int)C);
    twosmallest_kernel<<<(int)L, 256, 0, stream>>>(cosine, min2, (int)L);
    greedy_kernel<<<1, 256, 0, stream>>>(cosine, min2, sel, (int)L, (int)k);
}